// Round 1
// baseline (241.711 us; speedup 1.0000x reference)
//
#include <hip/hip_runtime.h>
#include <hip/hip_bf16.h>

typedef __attribute__((ext_vector_type(8))) short short8;
typedef __attribute__((ext_vector_type(4))) short short4_t;
typedef __attribute__((ext_vector_type(4))) float float4_;

#define LOG2E 1.4426950408889634f

__device__ __forceinline__ short f2bf(float f) {
    unsigned int u = __builtin_bit_cast(unsigned int, f);
    u = (u + 0x7FFFu + ((u >> 16) & 1u)) >> 16;
    return (short)u;
}

__device__ __forceinline__ void gload_lds16(const short* g, short* l) {
    __builtin_amdgcn_global_load_lds((const __attribute__((address_space(1))) void*)g,
                                     (__attribute__((address_space(3))) void*)l, 16, 0, 0);
}

// ---------------- convert fp32 -> bf16 (fold SCALE*LOG2E into Wq) ----------------
__global__ __launch_bounds__(256) void cvt_kernel(
    const float* __restrict__ X, const float* __restrict__ Wq, const float* __restrict__ Wk,
    const float* __restrict__ Wv, const float* __restrict__ Wo,
    short* __restrict__ Xb, short* __restrict__ Wqkb, short* __restrict__ Wvb, short* __restrict__ Wob) {
    int i = blockIdx.x * 256 + threadIdx.x;
    const float* src; short* dst; float sc = 1.0f;
    if (i < 1048576) { src = X + (size_t)i * 4; dst = Xb + (size_t)i * 4; }
    else {
        int w = i - 1048576; int sec = w >> 16; int j = (w & 65535) * 4;
        if (sec == 0)      { src = Wq + j; dst = Wqkb + j; sc = 0.125f * LOG2E; }
        else if (sec == 1) { src = Wk + j; dst = Wqkb + 262144 + j; }
        else if (sec == 2) { src = Wv + j; dst = Wvb + j; }
        else               { src = Wo + j; dst = Wob + j; }
    }
    float4 v = *(const float4*)src;
    short4_t o;
    o[0] = f2bf(v.x * sc); o[1] = f2bf(v.y * sc); o[2] = f2bf(v.z * sc); o[3] = f2bf(v.w * sc);
    *(short4_t*)dst = o;
}

// ---------------- m97-style GEMM, C[m,n] = sum_k A[m,k]*B[n,k] ----------------
// MODE 0: A=Xbf[8192x512], B=Wqk[1024x512] -> scatter bf16 into Q ([b,h,n,dh]) and K
// MODE 1: A=Wvb[512x512], B=Xbf+z*2048*512 -> Vt + z*512*2048, bf16 [dv][n]
// MODE 2: A=AObf[8192x512], B=Wout[512x512] -> fp32 d_out [m*512+n]
template<int MODE>
__global__ __launch_bounds__(256) void gemm_bt(const short* __restrict__ A, const short* __restrict__ B,
                                               void* __restrict__ C, short* __restrict__ C2) {
    __shared__ short At[128 * 32];
    __shared__ short Bt[128 * 32];
    constexpr int K = 512;
    int tid = threadIdx.x;
    int wid = tid >> 6, lane = tid & 63;
    int quad = lane >> 4, cc = lane & 15;
    int wr = wid >> 1, wc = wid & 1;
    int m0 = blockIdx.y * 128, n0 = blockIdx.x * 128;
    const short* Ag = A;
    const short* Bg = (MODE == 1) ? (B + (size_t)blockIdx.z * 2048 * 512) : B;

    float4_ acc[4][4] = {};

    for (int kk = 0; kk < K; kk += 32) {
#pragma unroll
        for (int i = 0; i < 2; ++i) {
            int lb = wid * 1024 + i * 4096 + lane * 16;   // byte offset in 8KB tile
            int row = lb >> 6;                             // 64B per row (32 bf16)
            int ke = (lb & 63) >> 1;                       // element offset in row
            gload_lds16(Ag + (size_t)(m0 + row) * K + kk + ke, At + (lb >> 1));
            gload_lds16(Bg + (size_t)(n0 + row) * K + kk + ke, Bt + (lb >> 1));
        }
        __syncthreads();
        short8 af[4], bf[4];
#pragma unroll
        for (int i = 0; i < 4; ++i) af[i] = *(const short8*)(At + (wr * 64 + i * 16 + cc) * 32 + quad * 8);
#pragma unroll
        for (int j = 0; j < 4; ++j) bf[j] = *(const short8*)(Bt + (wc * 64 + j * 16 + cc) * 32 + quad * 8);
#pragma unroll
        for (int i = 0; i < 4; ++i)
#pragma unroll
            for (int j = 0; j < 4; ++j)
                acc[i][j] = __builtin_amdgcn_mfma_f32_16x16x32_bf16(af[i], bf[j], acc[i][j], 0, 0, 0);
        __syncthreads();
    }

#pragma unroll
    for (int i = 0; i < 4; ++i) {
#pragma unroll
        for (int j = 0; j < 4; ++j) {
#pragma unroll
            for (int r = 0; r < 4; ++r) {
                int gm = m0 + wr * 64 + i * 16 + quad * 4 + r;
                int gn = n0 + wc * 64 + j * 16 + cc;
                float v = acc[i][j][r];
                if (MODE == 0) {
                    int which = gn >> 9;       // 0=Q, 1=K
                    int hd = gn & 511;
                    int h = hd >> 6, dh = hd & 63;
                    int b = gm >> 11, nn = gm & 2047;
                    short* dst = (which ? C2 : (short*)C);
                    dst[((((size_t)b * 8 + h) * 2048 + nn) * 64) + dh] = f2bf(v);
                } else if (MODE == 1) {
                    ((short*)C)[(size_t)blockIdx.z * 512 * 2048 + (size_t)gm * 2048 + gn] = f2bf(v);
                } else {
                    ((float*)C)[(size_t)gm * 512 + gn] = v;
                }
            }
        }
    }
}

// ---------------- flash attention, exp2 domain (SCALE*LOG2E folded into Q) ----------------
// grid (32 q-tiles, 32 b*h); block 256 = 4 waves, each wave 16 q-rows; s-tiles of 128
__global__ __launch_bounds__(256) void attn_kernel(const short* __restrict__ Q, const short* __restrict__ Kg,
                                                   const short* __restrict__ Vt, const int* __restrict__ mask,
                                                   short* __restrict__ AO) {
    __shared__ short Kt[128 * 72];       // [s][dh], pad 64->72
    __shared__ short Vtt[64 * 136];      // [dh][s], pad 128->136
    __shared__ short Pt[4][16 * 136];    // per-wave P tile [t][s]
    __shared__ int mt[128];

    int tid = threadIdx.x;
    int wid = tid >> 6, lane = tid & 63;
    int quad = lane >> 4, cc = lane & 15;
    int bh = blockIdx.y;
    int b = bh >> 3, h = bh & 7;
    int q0 = blockIdx.x * 64;
    size_t base = (size_t)bh * 2048 * 64;

    int qrow = q0 + wid * 16 + cc;
    short8 qf0 = *(const short8*)(Q + base + (size_t)qrow * 64 + quad * 8);
    short8 qf1 = *(const short8*)(Q + base + (size_t)qrow * 64 + 32 + quad * 8);

    float m2[4], l[4];
    float4_ o[4] = {};
#pragma unroll
    for (int r = 0; r < 4; ++r) { m2[r] = -3.0e38f; l[r] = 0.0f; }
    const float MC = 1e-9f * LOG2E;

    for (int s0 = 0; s0 < 2048; s0 += 128) {
        // stage K [128][64] and Vt [64][128] tiles
#pragma unroll
        for (int i = 0; i < 4; ++i) {
            int vid = tid + i * 256;
            int s = vid >> 3, e = (vid & 7) * 8;
            *(short8*)(Kt + s * 72 + e) = *(const short8*)(Kg + base + (size_t)(s0 + s) * 64 + e);
            int d = vid >> 4, e2 = (vid & 15) * 8;
            *(short8*)(Vtt + d * 136 + e2) = *(const short8*)(Vt + base + (size_t)d * 2048 + s0 + e2);
        }
        if (tid < 128) mt[tid] = mask[b * 2048 + s0 + tid];
        __syncthreads();

        // scores (already in exp2 domain): xs[cb][r], row t = quad*4+r, col s = cb*16+cc
        float xs[8][4];
#pragma unroll
        for (int cb = 0; cb < 8; ++cb) {
            float4_ sc = {0.0f, 0.0f, 0.0f, 0.0f};
            sc = __builtin_amdgcn_mfma_f32_16x16x32_bf16(qf0, *(const short8*)(Kt + (cb * 16 + cc) * 72 + quad * 8), sc, 0, 0, 0);
            sc = __builtin_amdgcn_mfma_f32_16x16x32_bf16(qf1, *(const short8*)(Kt + (cb * 16 + cc) * 72 + 32 + quad * 8), sc, 0, 0, 0);
            bool mz = (mt[cb * 16 + cc] == 0);
#pragma unroll
            for (int r = 0; r < 4; ++r) xs[cb][r] = mz ? MC : sc[r];
        }
        // online softmax stats
        float tm[4], rs[4], al[4];
#pragma unroll
        for (int r = 0; r < 4; ++r) {
            float t = xs[0][r];
#pragma unroll
            for (int cb = 1; cb < 8; ++cb) t = fmaxf(t, xs[cb][r]);
#pragma unroll
            for (int d = 1; d < 16; d <<= 1) t = fmaxf(t, __shfl_xor(t, d));
            tm[r] = t;
            float mn = fmaxf(m2[r], t);
            al[r] = exp2f(m2[r] - mn);
            m2[r] = mn;
        }
#pragma unroll
        for (int cb = 0; cb < 8; ++cb)
#pragma unroll
            for (int r = 0; r < 4; ++r) xs[cb][r] = exp2f(xs[cb][r] - m2[r]);
#pragma unroll
        for (int r = 0; r < 4; ++r) {
            float s = 0.0f;
#pragma unroll
            for (int cb = 0; cb < 8; ++cb) s += xs[cb][r];
#pragma unroll
            for (int d = 1; d < 16; d <<= 1) s += __shfl_xor(s, d);
            rs[r] = s;
            l[r] = l[r] * al[r] + rs[r];
        }
#pragma unroll
        for (int dcb = 0; dcb < 4; ++dcb)
#pragma unroll
            for (int r = 0; r < 4; ++r) o[dcb][r] *= al[r];
        // write P (C-layout -> A-layout via per-wave LDS)
#pragma unroll
        for (int cb = 0; cb < 8; ++cb)
#pragma unroll
            for (int r = 0; r < 4; ++r)
                Pt[wid][(quad * 4 + r) * 136 + cb * 16 + cc] = f2bf(xs[cb][r]);
        __asm__ volatile("s_waitcnt lgkmcnt(0)" ::: "memory");
        // PV
#pragma unroll
        for (int kc = 0; kc < 4; ++kc) {
            short8 af = *(const short8*)(Pt[wid] + cc * 136 + kc * 32 + quad * 8);
#pragma unroll
            for (int dcb = 0; dcb < 4; ++dcb)
                o[dcb] = __builtin_amdgcn_mfma_f32_16x16x32_bf16(
                    af, *(const short8*)(Vtt + (dcb * 16 + cc) * 136 + kc * 32 + quad * 8), o[dcb], 0, 0, 0);
        }
        __syncthreads();
    }

    float inv[4];
#pragma unroll
    for (int r = 0; r < 4; ++r) inv[r] = 1.0f / l[r];
#pragma unroll
    for (int dcb = 0; dcb < 4; ++dcb)
#pragma unroll
        for (int r = 0; r < 4; ++r) {
            int n = q0 + wid * 16 + quad * 4 + r;
            AO[((size_t)(b * 2048 + n)) * 512 + h * 64 + dcb * 16 + cc] = f2bf(o[dcb][r] * inv[r]);
        }
}

extern "C" void kernel_launch(void* const* d_in, const int* in_sizes, int n_in,
                              void* d_out, int out_size, void* d_ws, size_t ws_size,
                              hipStream_t stream) {
    const float* X  = (const float*)d_in[0];
    const int* mask = (const int*)d_in[1];
    const float* Wq = (const float*)d_in[2];
    const float* Wk = (const float*)d_in[3];
    const float* Wv = (const float*)d_in[4];
    const float* Wo = (const float*)d_in[5];
    float* out = (float*)d_out;

    char* ws = (char*)d_ws;
    short* Xbf  = (short*)(ws + 0);              // 8192*512*2      = 8,388,608
    short* Wqkb = (short*)(ws + 8388608);        // 1024*512*2      = 1,048,576
    short* Wvb  = (short*)(ws + 9437184);        // 512*512*2       =   524,288
    short* Wob  = (short*)(ws + 9961472);        // 512*512*2       =   524,288
    short* Qb   = (short*)(ws + 10485760);       // [b,h,n,dh] bf16 = 8,388,608
    short* Kb   = (short*)(ws + 18874368);       // [b,h,n,dh] bf16 = 8,388,608
    short* Vtb  = (short*)(ws + 27262976);       // [b,dv,n]  bf16  = 8,388,608
    short* AOb  = (short*)(ws + 35651584);       // [b,n,512] bf16  = 8,388,608

    cvt_kernel<<<5120, 256, 0, stream>>>(X, Wq, Wk, Wv, Wo, Xbf, Wqkb, Wvb, Wob);
    gemm_bt<0><<<dim3(8, 64, 1), 256, 0, stream>>>(Xbf, Wqkb, (void*)Qb, Kb);
    gemm_bt<1><<<dim3(16, 4, 4), 256, 0, stream>>>(Wvb, Xbf, (void*)Vtb, nullptr);
    attn_kernel<<<dim3(32, 32), 256, 0, stream>>>(Qb, Kb, Vtb, mask, AOb);
    gemm_bt<2><<<dim3(4, 64, 1), 256, 0, stream>>>(AOb, Wob, d_out, nullptr);
}